// Round 1
// baseline (197.966 us; speedup 1.0000x reference)
//
#include <hip/hip_runtime.h>
#include <hip/hip_bf16.h>

#define B_N 32
#define S_N 2048
#define D_N 64
#define QBLK 64
#define KVBLK 64
#define PADW 72  // padded row width (fp16 elems): 144B rows, 16B-aligned

typedef _Float16 __attribute__((ext_vector_type(8))) half8;
typedef _Float16 __attribute__((ext_vector_type(4))) half4;
typedef float __attribute__((ext_vector_type(4))) floatx4;

__global__ __launch_bounds__(256) void sdpa_fwd_kernel(
    const float* __restrict__ Q, const float* __restrict__ K,
    const float* __restrict__ V, float* __restrict__ O) {
  const int tid = threadIdx.x;
  const int wave = tid >> 6;
  const int lane = tid & 63;
  const int g = lane >> 4;   // 16-lane group 0..3
  const int c = lane & 15;   // lane within group
  const int b = blockIdx.y;
  const int qtile = blockIdx.x;

  __shared__ _Float16 Klds[KVBLK * PADW];      // K tile, row-major [kv][d]
  __shared__ _Float16 Vtlds[D_N * PADW];       // V tile, transposed [d][kv], granule-swizzled
  __shared__ _Float16 Plds[4 * 16 * PADW];     // per-wave P buffer [q][kv]

  const size_t bbase = (size_t)b * S_N * D_N;
  const int qrow = qtile * QBLK + wave * 16 + c;

  // ---- Q fragments (B-operand layout == A layout: row=c, k=g*8..g*8+7), scaled by 1/8
  half8 qf[2];
  {
    const float* qp = Q + bbase + (size_t)qrow * D_N;
#pragma unroll
    for (int h = 0; h < 2; ++h) {
      const floatx4* s = (const floatx4*)(qp + h * 32 + g * 8);
      floatx4 a = s[0], bb = s[1];
#pragma unroll
      for (int e = 0; e < 4; ++e) {
        qf[h][e]     = (_Float16)(a[e] * 0.125f);
        qf[h][e + 4] = (_Float16)(bb[e] * 0.125f);
      }
    }
  }

  floatx4 oacc[4];
  const floatx4 zero4 = {0.f, 0.f, 0.f, 0.f};
#pragma unroll
  for (int dg = 0; dg < 4; ++dg) oacc[dg] = zero4;
  float mrun = -__builtin_inff();
  float lrun = 0.f;

  _Float16* pw = &Plds[wave * 16 * PADW];
  const int kvp = tid >> 3;  // 0..31: kv row-pair for V staging
  const int dcc = tid & 7;   // d chunk (8 elems) for V staging

  for (int t = 0; t < S_N / KVBLK; ++t) {
    const int kv0 = t * KVBLK;
    const float* kb = K + bbase + (size_t)kv0 * D_N;
    const float* vb = V + bbase + (size_t)kv0 * D_N;

    // ---- stage K tile (contiguous 16KB fp32) -> Klds, coalesced float4 x4/thread
#pragma unroll
    for (int j = 0; j < 2; ++j) {
      int gi = j * 256 + tid;        // granule of 8 elems
      int row = gi >> 3, cg = gi & 7;
      const floatx4* s = (const floatx4*)(kb + gi * 8);
      floatx4 a = s[0], bb = s[1];
      half8 hv;
#pragma unroll
      for (int e = 0; e < 4; ++e) {
        hv[e]     = (_Float16)a[e];
        hv[e + 4] = (_Float16)bb[e];
      }
      *(half8*)(&Klds[row * PADW + cg * 8]) = hv;
    }

    // ---- stage V transposed: Vtlds[d][kv], pack kv-pairs as u32, XOR-swizzle 16B granules
    {
      const floatx4* s0 = (const floatx4*)(vb + (2 * kvp) * D_N + dcc * 8);
      const floatx4* s1 = (const floatx4*)(vb + (2 * kvp + 1) * D_N + dcc * 8);
      floatx4 r0a = s0[0], r0b = s0[1], r1a = s1[0], r1b = s1[1];
#pragma unroll
      for (int jj = 0; jj < 8; ++jj) {
        int d = dcc * 8 + jj;
        float va  = (jj < 4) ? r0a[jj] : r0b[jj - 4];
        float vbv = (jj < 4) ? r1a[jj] : r1b[jj - 4];
        unsigned short ua = __builtin_bit_cast(unsigned short, (_Float16)va);
        unsigned short ub = __builtin_bit_cast(unsigned short, (_Float16)vbv);
        unsigned int pk = (unsigned int)ua | ((unsigned int)ub << 16);
        int gg = (kvp >> 2) ^ (d & 7);  // 16B-granule swizzle within row
        *(unsigned int*)((char*)Vtlds + d * (PADW * 2) + gg * 16 + (kvp & 3) * 4) = pk;
      }
    }
    __syncthreads();

    // ---- S^T = K_tile x Q^T : lane holds S^T[16*jg + 4g + i][q0 + c]
    floatx4 st[4];
#pragma unroll
    for (int jg = 0; jg < 4; ++jg) {
      floatx4 acc = zero4;
#pragma unroll
      for (int h = 0; h < 2; ++h) {
        half8 kf = *(const half8*)(&Klds[(jg * 16 + c) * PADW + h * 32 + g * 8]);
        acc = __builtin_amdgcn_mfma_f32_16x16x32_f16(kf, qf[h], acc, 0, 0, 0);
      }
      st[jg] = acc;
    }

    // ---- online softmax: lanes {c, c+16, c+32, c+48} share one q column
    float tmax = st[0][0];
#pragma unroll
    for (int jg = 0; jg < 4; ++jg)
#pragma unroll
      for (int i = 0; i < 4; ++i) tmax = fmaxf(tmax, st[jg][i]);
    tmax = fmaxf(tmax, __shfl_xor(tmax, 16));
    tmax = fmaxf(tmax, __shfl_xor(tmax, 32));
    float mnew = fmaxf(mrun, tmax);
    float alpha = __expf(mrun - mnew);  // exp(-inf)=0 on first tile
    float psum = 0.f;
#pragma unroll
    for (int jg = 0; jg < 4; ++jg) {
#pragma unroll
      for (int i = 0; i < 4; ++i) {
        float p = __expf(st[jg][i] - mnew);
        st[jg][i] = p;
        psum += p;
      }
    }
    psum += __shfl_xor(psum, 16);
    psum += __shfl_xor(psum, 32);
    lrun = lrun * alpha + psum;
    mrun = mnew;
#pragma unroll
    for (int dg = 0; dg < 4; ++dg) oacc[dg] *= alpha;

    // ---- P -> per-wave LDS as [q][kv]; 4 consecutive kv per reg group -> b64 writes
#pragma unroll
    for (int jg = 0; jg < 4; ++jg) {
      half4 p4;
#pragma unroll
      for (int i = 0; i < 4; ++i) p4[i] = (_Float16)st[jg][i];
      *(half4*)(&pw[c * PADW + jg * 16 + 4 * g]) = p4;
    }

    // ---- O^T += V^T x P^T  (both operands ds_read_b128)
#pragma unroll
    for (int kh = 0; kh < 2; ++kh) {
      half8 pf = *(const half8*)(&pw[c * PADW + kh * 32 + g * 8]);
#pragma unroll
      for (int dg = 0; dg < 4; ++dg) {
        int d = dg * 16 + c;
        int gg = (kh * 4 + g) ^ (d & 7);
        half8 vf = *(const half8*)((char*)Vtlds + d * (PADW * 2) + gg * 16);
        oacc[dg] = __builtin_amdgcn_mfma_f32_16x16x32_f16(vf, pf, oacc[dg], 0, 0, 0);
      }
    }
    __syncthreads();
  }

  // ---- epilogue: lane holds O[q0+c][dg*16 + 4g + i]
  float inv = 1.0f / lrun;
  float* op = O + bbase + (size_t)qrow * D_N;
#pragma unroll
  for (int dg = 0; dg < 4; ++dg) {
    floatx4 ov = oacc[dg] * inv;
    *(floatx4*)(&op[dg * 16 + 4 * g]) = ov;
  }
}

extern "C" void kernel_launch(void* const* d_in, const int* in_sizes, int n_in,
                              void* d_out, int out_size, void* d_ws, size_t ws_size,
                              hipStream_t stream) {
  const float* q = (const float*)d_in[0];
  const float* k = (const float*)d_in[1];
  const float* v = (const float*)d_in[2];
  float* o = (float*)d_out;
  dim3 grid(S_N / QBLK, B_N);
  sdpa_fwd_kernel<<<grid, dim3(256), 0, stream>>>(q, k, v, o);
}

// Round 3
// 145.816 us; speedup vs baseline: 1.3576x; 1.3576x over previous
//
#include <hip/hip_runtime.h>

#define S_N 2048
#define D_H 64
#define KVB 64
#define NT (S_N / KVB)  // 32

typedef _Float16 half8 __attribute__((ext_vector_type(8)));
typedef float floatx4 __attribute__((ext_vector_type(4)));
typedef float floatx16 __attribute__((ext_vector_type(16)));
typedef unsigned int uint2v __attribute__((ext_vector_type(2)));

__device__ __forceinline__ unsigned pkh(float a, float b) {
  return __builtin_bit_cast(unsigned, __builtin_amdgcn_cvt_pkrtz(a, b));
}
__device__ __forceinline__ float bcf(unsigned u) { return __builtin_bit_cast(float, u); }
__device__ __forceinline__ unsigned bcu(float f) { return __builtin_bit_cast(unsigned, f); }

// XOR swizzle: 16B-granule permutation within a 64-elem (128B) row.
// sigma(r) = ((r&7) + ((r>>3)&7)) & 7  -- includes r>>3 so the V u32-scatter
// staging writes (d = dc8*8+jj) keep dc8 in the bank index (<=2-way).
__device__ __forceinline__ int sig(int r) { return ((r & 7) + ((r >> 3) & 7)) & 7; }

__global__ __launch_bounds__(256, 2) void sdpa_kernel(
    const float* __restrict__ Q, const float* __restrict__ K,
    const float* __restrict__ V, float* __restrict__ O) {
  const int tid = threadIdx.x;
  const int wv = tid >> 6;
  const int l = tid & 63;
  const int c31 = l & 31;
  const int hi = l >> 5;

  __shared__ _Float16 KS[2][KVB * D_H];  // [kv][d], granule-swizzled
  __shared__ _Float16 VS[2][D_H * KVB];  // [d][kv] (transposed), granule-swizzled

  const size_t bbase = (size_t)blockIdx.y * S_N * D_H;
  const int qbase = blockIdx.x * 128 + wv * 32;
  const int qrow = qbase + c31;

  const float SCL = 0.125f * 1.44269504088896f;  // log2(e)/sqrt(d_k): exp2-domain softmax

  // ---- Q fragments: lane holds Q[q=c31][d = 16kc + 8hi + 0..7], scaled
  half8 qf[4];
#pragma unroll
  for (int kc = 0; kc < 4; ++kc) {
    const float* qp = Q + bbase + (size_t)qrow * D_H + kc * 16 + hi * 8;
    floatx4 x = *(const floatx4*)qp;
    floatx4 y = *(const floatx4*)(qp + 4);
    union { unsigned u[4]; half8 h; } uu = {{
        pkh(x[0] * SCL, x[1] * SCL), pkh(x[2] * SCL, x[3] * SCL),
        pkh(y[0] * SCL, y[1] * SCL), pkh(y[2] * SCL, y[3] * SCL)}};
    qf[kc] = uu.h;
  }

  // ---- staging maps (256 threads)
  const int kr_ = tid >> 3;  // 0..31
  const int kg8 = tid & 7;   // granule / d-chunk

  floatx4 kreg[2][2], vreg[2][2];

  auto loadKV = [&](int kv0) {
#pragma unroll
    for (int it = 0; it < 2; ++it) {
      const float* kp = K + bbase + (size_t)(kv0 + it * 32 + kr_) * D_H + kg8 * 8;
      kreg[it][0] = *(const floatx4*)kp;
      kreg[it][1] = *(const floatx4*)(kp + 4);
    }
#pragma unroll
    for (int r = 0; r < 2; ++r) {
      const float* vp = V + bbase + (size_t)(kv0 + 2 * kr_ + r) * D_H + kg8 * 8;
      vreg[r][0] = *(const floatx4*)vp;
      vreg[r][1] = *(const floatx4*)(vp + 4);
    }
  };

  auto writeKV = [&](int buf) {
#pragma unroll
    for (int it = 0; it < 2; ++it) {
      int row = it * 32 + kr_;
      int g = kg8 ^ sig(row);
      union { unsigned u[4]; half8 h; } uu = {{
          pkh(kreg[it][0][0], kreg[it][0][1]), pkh(kreg[it][0][2], kreg[it][0][3]),
          pkh(kreg[it][1][0], kreg[it][1][1]), pkh(kreg[it][1][2], kreg[it][1][3])}};
      *(half8*)(&KS[buf][row * 64 + g * 8]) = uu.h;
    }
#pragma unroll
    for (int jj = 0; jj < 8; ++jj) {
      int d = kg8 * 8 + jj;
      int g = (kr_ >> 2) ^ ((jj + kg8) & 7);  // == (kvpair>>2) ^ sig(d)
      unsigned val = pkh(vreg[0][jj >> 2][jj & 3], vreg[1][jj >> 2][jj & 3]);
      *(unsigned*)((char*)&VS[buf][0] + d * 128 + g * 16 + (kr_ & 3) * 4) = val;
    }
  };

  floatx16 oo[2] = {{0,0,0,0,0,0,0,0,0,0,0,0,0,0,0,0},
                    {0,0,0,0,0,0,0,0,0,0,0,0,0,0,0,0}};
  float m_ = -__builtin_inff();
  float l_ = 0.0f;

  // prologue: stage tile 0
  loadKV(0);
  writeKV(0);
  __syncthreads();

  for (int t = 0; t < NT; ++t) {
    const int cur = t & 1;
    const bool pf = (t + 1) < NT;
    if (pf) loadKV((t + 1) * KVB);  // issue early; latency hides under QK

    // ---- S^T = K_tile x Q^T : lane holds S^T[kv(r,hi)+32*kvsub][q = c31]
    floatx16 st0 = {0,0,0,0,0,0,0,0,0,0,0,0,0,0,0,0};
    floatx16 st1 = {0,0,0,0,0,0,0,0,0,0,0,0,0,0,0,0};
    {
      const int sg0 = sig(c31), sg1 = sig(32 + c31);
#pragma unroll
      for (int kc = 0; kc < 4; ++kc) {
        half8 kf0 = *(const half8*)(&KS[cur][c31 * 64 + (((2 * kc + hi) ^ sg0) * 8)]);
        st0 = __builtin_amdgcn_mfma_f32_32x32x16_f16(kf0, qf[kc], st0, 0, 0, 0);
        half8 kf1 = *(const half8*)(&KS[cur][(32 + c31) * 64 + (((2 * kc + hi) ^ sg1) * 8)]);
        st1 = __builtin_amdgcn_mfma_f32_32x32x16_f16(kf1, qf[kc], st1, 0, 0, 0);
      }
    }

    // ---- online softmax, fully in-register (lane = one q column; partner = l^32)
    float tm = st0[0];
#pragma unroll
    for (int r = 1; r < 16; ++r) tm = fmaxf(tm, st0[r]);
#pragma unroll
    for (int r = 0; r < 16; ++r) tm = fmaxf(tm, st1[r]);
    {
      uint2v rr = __builtin_amdgcn_permlane32_swap(bcu(tm), bcu(tm), false, false);
      tm = fmaxf(bcf(rr[0]), bcf(rr[1]));
    }
    bool skip = __all(tm <= m_ + 8.0f);  // defer-max: P bounded by 2^8
    float mn = skip ? m_ : fmaxf(m_, tm);
    float alpha = skip ? 1.0f : __builtin_amdgcn_exp2f(m_ - mn);
    m_ = mn;
    float ps = 0.0f;
#pragma unroll
    for (int r = 0; r < 16; ++r) { float p = __builtin_amdgcn_exp2f(st0[r] - mn); st0[r] = p; ps += p; }
#pragma unroll
    for (int r = 0; r < 16; ++r) { float p = __builtin_amdgcn_exp2f(st1[r] - mn); st1[r] = p; ps += p; }
    {
      uint2v rr = __builtin_amdgcn_permlane32_swap(bcu(ps), bcu(ps), false, false);
      ps = bcf(rr[0]) + bcf(rr[1]);
    }
    if (!skip) {
      l_ *= alpha;
#pragma unroll
      for (int r = 0; r < 16; ++r) { oo[0][r] *= alpha; oo[1][r] *= alpha; }
    }
    l_ += ps;

    // ---- P -> fp16 A/B-fragments in-register (cvt_pkrtz + permlane32_swap, no LDS)
    unsigned wds[16];
#pragma unroll
    for (int j = 0; j < 8; ++j) wds[j] = pkh(st0[2 * j], st0[2 * j + 1]);
#pragma unroll
    for (int j = 0; j < 8; ++j) wds[8 + j] = pkh(st1[2 * j], st1[2 * j + 1]);
    half8 pfrag[4];
#pragma unroll
    for (int kcc = 0; kcc < 4; ++kcc) {
      int base = (kcc >> 1) * 8 + 4 * (kcc & 1);
      uint2v r0 = __builtin_amdgcn_permlane32_swap(wds[base + 0], wds[base + 2], false, false);
      uint2v r1 = __builtin_amdgcn_permlane32_swap(wds[base + 1], wds[base + 3], false, false);
      union { unsigned u[4]; half8 h; } uu = {{r0[0], r1[0], r0[1], r1[1]}};
      pfrag[kcc] = uu.h;
    }

    // ---- write next tile to the other buffer (loads have had QK+softmax to land)
    if (pf) writeKV(cur ^ 1);

    // ---- O^T += V^T x P^T
#pragma unroll
    for (int dsub = 0; dsub < 2; ++dsub) {
      const int row = dsub * 32 + c31;
      const int sg = sig(row);
#pragma unroll
      for (int kcc = 0; kcc < 4; ++kcc) {
        half8 vf = *(const half8*)(&VS[cur][row * 64 + (((2 * kcc + hi) ^ sg) * 8)]);
        oo[dsub] = __builtin_amdgcn_mfma_f32_32x32x16_f16(vf, pfrag[kcc], oo[dsub], 0, 0, 0);
      }
    }

    __syncthreads();
  }

  // ---- epilogue: lane holds O^T[d = 32dsub + 8u + 4hi + i][q = qrow]
  float inv = 1.0f / l_;
  float* op = O + bbase + (size_t)qrow * D_H;
#pragma unroll
  for (int dsub = 0; dsub < 2; ++dsub) {
#pragma unroll
    for (int u = 0; u < 4; ++u) {
      floatx4 w;
#pragma unroll
      for (int i = 0; i < 4; ++i) w[i] = oo[dsub][4 * u + i] * inv;
      *(floatx4*)(op + dsub * 32 + u * 8 + hi * 4) = w;
    }
  }
}

extern "C" void kernel_launch(void* const* d_in, const int* in_sizes, int n_in,
                              void* d_out, int out_size, void* d_ws, size_t ws_size,
                              hipStream_t stream) {
  const float* q = (const float*)d_in[0];
  const float* k = (const float*)d_in[1];
  const float* v = (const float*)d_in[2];
  float* o = (float*)d_out;
  dim3 grid(S_N / 128, 32);
  sdpa_kernel<<<grid, dim3(256), 0, stream>>>(q, k, v, o);
}